// Round 1
// baseline (4715.782 us; speedup 1.0000x reference)
//
#include <hip/hip_runtime.h>
#include <math.h>

#define NPTS 2048
#define NB 8
#define BN 16384   // NB*NPTS
#define KNN 16

// ---------------- sq: per-node squared norm ----------------
__global__ __launch_bounds__(256) void sq_kernel(const float* __restrict__ X,
                                                 float* __restrict__ SQ, int din) {
    int g = blockIdx.x * 256 + threadIdx.x;
    if (g >= BN) return;
    const float* row = X + (size_t)g * din;
    float s = 0.f;
    for (int d = 0; d < din; ++d) s = fmaf(row[d], row[d], s);
    SQ[g] = s;
}

// ---------------- prep: Wcat = [W1top - W1bot | W1bot], bcat = [b1 | 0] ----------------
__global__ __launch_bounds__(256) void prep_wcat_kernel(const float* __restrict__ W1,
                                                        const float* __restrict__ b1,
                                                        float* __restrict__ Wcat,
                                                        float* __restrict__ bcat,
                                                        int din, int d2) {
    int n4 = 2 * d2;
    int total = din * n4;
    int i = blockIdx.x * 256 + threadIdx.x;
    if (i < total) {
        int d = i / n4, c = i - d * n4;
        float v;
        if (c < d2) v = W1[d * d2 + c] - W1[(din + d) * d2 + c];
        else        v = W1[(din + d) * d2 + (c - d2)];
        Wcat[i] = v;
    }
    if (i < n4) bcat[i] = (i < d2) ? b1[i] : 0.f;
}

// ---------------- knn: fused distance + top-16 (4 queries / block) ----------------
template <int DIN>
__global__ __launch_bounds__(256) void knn_kernel(const float* __restrict__ X,
                                                  const float* __restrict__ SQ,
                                                  int* __restrict__ IDX) {
    __shared__ float dist[4][NPTS];
    __shared__ float xq[4][(DIN < 4) ? 4 : DIN];
    __shared__ float sqq[4];
    const int t = threadIdx.x;
    const int qbase = blockIdx.x * 4;
    const int jbase = (qbase / NPTS) * NPTS;

    for (int i = t; i < 4 * DIN; i += 256) {
        int q = i / DIN, d = i - q * DIN;
        xq[q][d] = X[(size_t)(qbase + q) * DIN + d];
    }
    if (t < 4) sqq[t] = SQ[qbase + t];
    __syncthreads();

    for (int j0 = 0; j0 < NPTS; j0 += 1024) {
        float acc[4][4];   // [u][q]
        #pragma unroll
        for (int u = 0; u < 4; ++u)
            #pragma unroll
            for (int q = 0; q < 4; ++q) acc[u][q] = 0.f;
        const float* xr0 = X + (size_t)(jbase + j0 + t) * DIN;
        if constexpr (DIN % 4 == 0) {
            for (int d = 0; d < DIN; d += 4) {
                float4 v[4];
                #pragma unroll
                for (int u = 0; u < 4; ++u)
                    v[u] = *(const float4*)(xr0 + (size_t)u * 256 * DIN + d);
                #pragma unroll
                for (int q = 0; q < 4; ++q) {
                    float w0 = xq[q][d], w1 = xq[q][d + 1], w2 = xq[q][d + 2], w3 = xq[q][d + 3];
                    #pragma unroll
                    for (int u = 0; u < 4; ++u) {
                        float a = acc[u][q];
                        a = fmaf(v[u].x, w0, a);
                        a = fmaf(v[u].y, w1, a);
                        a = fmaf(v[u].z, w2, a);
                        a = fmaf(v[u].w, w3, a);
                        acc[u][q] = a;
                    }
                }
            }
        } else {
            for (int d = 0; d < DIN; ++d) {
                #pragma unroll
                for (int q = 0; q < 4; ++q) {
                    float w = xq[q][d];
                    #pragma unroll
                    for (int u = 0; u < 4; ++u)
                        acc[u][q] = fmaf(xr0[(size_t)u * 256 * DIN + d], w, acc[u][q]);
                }
            }
        }
        #pragma unroll
        for (int u = 0; u < 4; ++u) {
            int j = j0 + t + u * 256;
            float sj = SQ[jbase + j];
            #pragma unroll
            for (int q = 0; q < 4; ++q)
                dist[q][j] = (sqq[q] + sj) - 2.f * acc[u][q];
        }
    }
    __syncthreads();

    const int w = t >> 6, lane = t & 63;
    for (int rep = 0; rep < KNN; ++rep) {
        float best = INFINITY;
        int bj = NPTS;
        for (int j = lane; j < NPTS; j += 64) {
            float v = dist[w][j];
            if (v < best) { best = v; bj = j; }   // ascending j -> smallest idx on ties
        }
        #pragma unroll
        for (int off = 32; off > 0; off >>= 1) {
            float ov = __shfl_down(best, off);
            int oj = __shfl_down(bj, off);
            if (ov < best || (ov == best && oj < bj)) { best = ov; bj = oj; }
        }
        if (lane == 0) {
            IDX[(size_t)(qbase + w) * KNN + rep] = bj;  // batch-local index
            dist[w][bj] = INFINITY;
        }
        __syncthreads();
    }
}

// ---------------- generic tiled GEMM: C[M,N] = A[M,K]@B[K,N] + bias ----------------
template <int KK, int NN>
__global__ __launch_bounds__(256) void gemm_pq_kernel(const float* __restrict__ A,
                                                      const float* __restrict__ B,
                                                      const float* __restrict__ bias,
                                                      float* __restrict__ C) {
    __shared__ float As[16][68];   // K-major: As[r][m]
    __shared__ float Bs[16][64];
    const int t = threadIdx.x;
    const int tx = t & 15, ty = t >> 4;
    const int m0 = blockIdx.x * 64;
    const int c0 = blockIdx.y * 64;
    float acc[4][4];
    #pragma unroll
    for (int i = 0; i < 4; ++i)
        #pragma unroll
        for (int j = 0; j < 4; ++j) acc[i][j] = 0.f;

    constexpr int KCH = (KK + 15) / 16;
    for (int kc = 0; kc < KCH; ++kc) {
        const int k0 = kc * 16;
        {   // A tile
            int m = t & 63;
            int r4 = (t >> 6) * 4;
            if constexpr (KK % 16 == 0) {
                float4 v = *(const float4*)(A + (size_t)(m0 + m) * KK + k0 + r4);
                As[r4 + 0][m] = v.x; As[r4 + 1][m] = v.y;
                As[r4 + 2][m] = v.z; As[r4 + 3][m] = v.w;
            } else {
                #pragma unroll
                for (int i = 0; i < 4; ++i) {
                    int r = r4 + i;
                    As[r][m] = (k0 + r < KK) ? A[(size_t)(m0 + m) * KK + k0 + r] : 0.f;
                }
            }
        }
        {   // B tile
            int r = t >> 4;
            int c = (t & 15) * 4;
            float4 v = make_float4(0.f, 0.f, 0.f, 0.f);
            if (k0 + r < KK) v = *(const float4*)(B + (size_t)(k0 + r) * NN + c0 + c);
            *(float4*)&Bs[r][c] = v;
        }
        __syncthreads();
        #pragma unroll
        for (int r = 0; r < 16; ++r) {
            float4 a4 = *(const float4*)&As[r][ty * 4];
            float4 b4 = *(const float4*)&Bs[r][tx * 4];
            float av[4] = {a4.x, a4.y, a4.z, a4.w};
            float bv[4] = {b4.x, b4.y, b4.z, b4.w};
            #pragma unroll
            for (int i = 0; i < 4; ++i)
                #pragma unroll
                for (int j = 0; j < 4; ++j)
                    acc[i][j] = fmaf(av[i], bv[j], acc[i][j]);
        }
        __syncthreads();
    }
    float4 bv4 = *(const float4*)(bias + c0 + tx * 4);
    float bv[4] = {bv4.x, bv4.y, bv4.z, bv4.w};
    #pragma unroll
    for (int i = 0; i < 4; ++i) {
        float4 o;
        o.x = acc[i][0] + bv[0];
        o.y = acc[i][1] + bv[1];
        o.z = acc[i][2] + bv[2];
        o.w = acc[i][3] + bv[3];
        *(float4*)(C + (size_t)(m0 + ty * 4 + i) * NN + c0 + tx * 4) = o;
    }
}

// ---------------- edge: gather relu(P_i+Q_j) -> @W2+b2 -> relu -> mean_k ----------------
template <int D2, int DOUT>
__global__ __launch_bounds__(256) void edge_kernel(const float* __restrict__ PQ,  // [BN][2*D2]
                                                   const int* __restrict__ IDX,
                                                   const float* __restrict__ W2,  // [D2][DOUT]
                                                   const float* __restrict__ b2,  // [DOUT]
                                                   float* __restrict__ Xn) {      // [BN][DOUT]
    constexpr int N4 = 2 * D2;
    __shared__ float As[16][68];   // K-major: As[r][edge]
    __shared__ float Bs[16][64];   // also reused as reduction buffer
    __shared__ int gjs[64];
    const int t = threadIdx.x;
    const int tx = t & 15, ty = t >> 4;
    const int nb = blockIdx.x * 4;      // node base (4 nodes = 64 edges)
    const int c0 = blockIdx.y * 64;

    if (t < 64) {
        int node = nb + (t >> 4);
        int bstart = (node / NPTS) * NPTS;
        gjs[t] = bstart + IDX[(size_t)node * KNN + (t & 15)];
    }
    __syncthreads();

    float acc[4][4];
    #pragma unroll
    for (int i = 0; i < 4; ++i)
        #pragma unroll
        for (int j = 0; j < 4; ++j) acc[i][j] = 0.f;

    const int e = t & 63;
    const int r4 = (t >> 6) * 4;
    const int gi = nb + (e >> 4);

    for (int k0 = 0; k0 < D2; k0 += 16) {
        {   // A tile: relu(P_i + Q_j)
            int gj = gjs[e];
            float4 p = *(const float4*)(PQ + (size_t)gi * N4 + k0 + r4);
            float4 q = *(const float4*)(PQ + (size_t)gj * N4 + D2 + k0 + r4);
            As[r4 + 0][e] = fmaxf(p.x + q.x, 0.f);
            As[r4 + 1][e] = fmaxf(p.y + q.y, 0.f);
            As[r4 + 2][e] = fmaxf(p.z + q.z, 0.f);
            As[r4 + 3][e] = fmaxf(p.w + q.w, 0.f);
        }
        {   // B tile (W2)
            int r = t >> 4;
            int c = (t & 15) * 4;
            float4 v = make_float4(0.f, 0.f, 0.f, 0.f);
            if (c0 + c < DOUT) v = *(const float4*)(W2 + (size_t)(k0 + r) * DOUT + c0 + c);
            *(float4*)&Bs[r][c] = v;
        }
        __syncthreads();
        #pragma unroll
        for (int r = 0; r < 16; ++r) {
            float4 a4 = *(const float4*)&As[r][ty * 4];
            float4 b4 = *(const float4*)&Bs[r][tx * 4];
            float av[4] = {a4.x, a4.y, a4.z, a4.w};
            float bv[4] = {b4.x, b4.y, b4.z, b4.w};
            #pragma unroll
            for (int i = 0; i < 4; ++i)
                #pragma unroll
                for (int j = 0; j < 4; ++j)
                    acc[i][j] = fmaf(av[i], bv[j], acc[i][j]);
        }
        __syncthreads();
    }

    // epilogue: +b2, relu, sum 4 rows per thread, then 4-way combine -> mean/16
    float bv[4];
    #pragma unroll
    for (int j = 0; j < 4; ++j) {
        int c = c0 + tx * 4 + j;
        bv[j] = (c < DOUT) ? b2[c] : 0.f;
    }
    float s[4];
    #pragma unroll
    for (int j = 0; j < 4; ++j) {
        float ss = 0.f;
        #pragma unroll
        for (int i = 0; i < 4; ++i) ss += fmaxf(acc[i][j] + bv[j], 0.f);
        s[j] = ss;
    }
    #pragma unroll
    for (int j = 0; j < 4; ++j) Bs[ty][tx * 4 + j] = s[j];
    __syncthreads();
    if ((ty & 3) == 0) {
        int node = nb + (ty >> 2);
        #pragma unroll
        for (int j = 0; j < 4; ++j) {
            int c = c0 + tx * 4 + j;
            if (c < DOUT) {
                int cc = tx * 4 + j;
                float tot = Bs[ty][cc] + Bs[ty + 1][cc] + Bs[ty + 2][cc] + Bs[ty + 3][cc];
                Xn[(size_t)node * DOUT + c] = tot * (1.f / 16.f);
            }
        }
    }
}

// ---------------- final: mean over nodes + 16x2 projection ----------------
__global__ __launch_bounds__(256) void final_kernel(const float* __restrict__ X,
                                                    const float* __restrict__ Wf,
                                                    const float* __restrict__ bfin,
                                                    float* __restrict__ out) {
    __shared__ float red[16][17];
    __shared__ float pool[16];
    const int b = blockIdx.x;
    const int t = threadIdx.x;
    const int c = t & 15, rg = t >> 4;
    float s = 0.f;
    for (int n = rg; n < NPTS; n += 16) s += X[(size_t)(b * NPTS + n) * 16 + c];
    red[rg][c] = s;
    __syncthreads();
    if (t < 16) {
        float tot = 0.f;
        #pragma unroll
        for (int i = 0; i < 16; ++i) tot += red[i][t];
        pool[t] = tot * (1.f / NPTS);
    }
    __syncthreads();
    if (t < 2) {
        float a = bfin[t];
        #pragma unroll
        for (int cc = 0; cc < 16; ++cc) a = fmaf(pool[cc], Wf[cc * 2 + t], a);
        out[b * 2 + t] = a;
    }
}

// ---------------- per-layer driver ----------------
template <int DIN, int DOUT>
static void run_layer(const float* Xin, float* Xout, float* PQ, float* SQ, int* IDX,
                      float* WCAT, float* BCAT,
                      const float* W1, const float* b1, const float* W2, const float* b2,
                      hipStream_t stream) {
    constexpr int D2 = 2 * DOUT;
    constexpr int N4 = 2 * D2;
    sq_kernel<<<BN / 256, 256, 0, stream>>>(Xin, SQ, DIN);
    knn_kernel<DIN><<<BN / 4, 256, 0, stream>>>(Xin, SQ, IDX);
    int prep_total = DIN * N4;
    prep_wcat_kernel<<<(prep_total + 255) / 256, 256, 0, stream>>>(W1, b1, WCAT, BCAT, DIN, D2);
    dim3 g1(BN / 64, N4 / 64);
    gemm_pq_kernel<DIN, N4><<<g1, 256, 0, stream>>>(Xin, WCAT, BCAT, PQ);
    dim3 g2(BN / 4, (DOUT + 63) / 64);
    edge_kernel<D2, DOUT><<<g2, 256, 0, stream>>>(PQ, IDX, W2, b2, Xout);
}

extern "C" void kernel_launch(void* const* d_in, const int* in_sizes, int n_in,
                              void* d_out, int out_size, void* d_ws, size_t ws_size,
                              hipStream_t stream) {
    (void)in_sizes; (void)n_in; (void)out_size; (void)ws_size;
    const float* x = (const float*)d_in[0];
    const float* W1a[6]; const float* b1a[6]; const float* W2a[6]; const float* b2a[6];
    for (int l = 0; l < 6; ++l) {
        W1a[l] = (const float*)d_in[1 + 4 * l];
        b1a[l] = (const float*)d_in[2 + 4 * l];
        W2a[l] = (const float*)d_in[3 + 4 * l];
        b2a[l] = (const float*)d_in[4 + 4 * l];
    }
    const float* Wf = (const float*)d_in[25];
    const float* bfin = (const float*)d_in[26];

    float* ws = (float*)d_ws;
    float* X0   = ws;                                   // 16384*256
    float* X1   = X0 + (size_t)BN * 256;                // 16384*256
    float* PQ   = X1 + (size_t)BN * 256;                // 16384*1024
    float* SQ   = PQ + (size_t)BN * 1024;               // 16384
    int*   IDX  = (int*)(SQ + BN);                      // 16384*16
    float* WCAT = (float*)(IDX + (size_t)BN * KNN);     // 131072
    float* BCAT = WCAT + 131072;                        // 1024

    run_layer<3,   32>(x,  X0, PQ, SQ, IDX, WCAT, BCAT, W1a[0], b1a[0], W2a[0], b2a[0], stream);
    run_layer<32, 128>(X0, X1, PQ, SQ, IDX, WCAT, BCAT, W1a[1], b1a[1], W2a[1], b2a[1], stream);
    run_layer<128,256>(X1, X0, PQ, SQ, IDX, WCAT, BCAT, W1a[2], b1a[2], W2a[2], b2a[2], stream);
    run_layer<256, 64>(X0, X1, PQ, SQ, IDX, WCAT, BCAT, W1a[3], b1a[3], W2a[3], b2a[3], stream);
    run_layer<64,  32>(X1, X0, PQ, SQ, IDX, WCAT, BCAT, W1a[4], b1a[4], W2a[4], b2a[4], stream);
    run_layer<32,  16>(X0, X1, PQ, SQ, IDX, WCAT, BCAT, W1a[5], b1a[5], W2a[5], b2a[5], stream);
    final_kernel<<<NB, 256, 0, stream>>>(X1, Wf, bfin, (float*)d_out);
}

// Round 2
// 3323.715 us; speedup vs baseline: 1.4188x; 1.4188x over previous
//
#include <hip/hip_runtime.h>
#include <math.h>

#define NPTS 2048
#define NB 8
#define BN 16384   // NB*NPTS
#define KNN 16

// ---------------- sq: per-node squared norm ----------------
__global__ __launch_bounds__(256) void sq_kernel(const float* __restrict__ X,
                                                 float* __restrict__ SQ, int din) {
    int g = blockIdx.x * 256 + threadIdx.x;
    if (g >= BN) return;
    const float* row = X + (size_t)g * din;
    float s = 0.f;
    for (int d = 0; d < din; ++d) s = fmaf(row[d], row[d], s);
    SQ[g] = s;
}

// ---------------- prep: Wcat = [W1top - W1bot | W1bot], bcat = [b1 | 0] ----------------
__global__ __launch_bounds__(256) void prep_wcat_kernel(const float* __restrict__ W1,
                                                        const float* __restrict__ b1,
                                                        float* __restrict__ Wcat,
                                                        float* __restrict__ bcat,
                                                        int din, int d2) {
    int n4 = 2 * d2;
    int total = din * n4;
    int i = blockIdx.x * 256 + threadIdx.x;
    if (i < total) {
        int d = i / n4, c = i - d * n4;
        float v;
        if (c < d2) v = W1[d * d2 + c] - W1[(din + d) * d2 + c];
        else        v = W1[(din + d) * d2 + (c - d2)];
        Wcat[i] = v;
    }
    if (i < n4) bcat[i] = (i < d2) ? b1[i] : 0.f;
}

// ---------------- knn: fused distance + top-16 (8 queries / block) ----------------
// dist LDS: 8*2048*4 = 64 KB (+xq) -> 2 blocks/CU. Each j-row float feeds 8 FMAs.
// Selection is per-wave barrier-free: wave w owns queries w and w+4; j == lane (mod 64)
// so the INF-poison write by the owner lane has no cross-lane LDS dependency.
template <int DIN>
__global__ __launch_bounds__(256) void knn_kernel(const float* __restrict__ X,
                                                  const float* __restrict__ SQ,
                                                  int* __restrict__ IDX) {
    __shared__ float dist[8][NPTS];
    __shared__ float xq[8][(DIN < 4) ? 4 : DIN];
    __shared__ float sqq[8];
    const int t = threadIdx.x;
    const int qbase = blockIdx.x * 8;
    const int jbase = (qbase / NPTS) * NPTS;

    for (int i = t; i < 8 * DIN; i += 256) {
        int q = i / DIN, d = i - q * DIN;
        xq[q][d] = X[(size_t)(qbase + q) * DIN + d];
    }
    if (t < 8) sqq[t] = SQ[qbase + t];
    __syncthreads();

    for (int j0 = 0; j0 < NPTS; j0 += 1024) {
        float acc[4][8];   // [u][q]
        #pragma unroll
        for (int u = 0; u < 4; ++u)
            #pragma unroll
            for (int q = 0; q < 8; ++q) acc[u][q] = 0.f;
        const float* xr0 = X + (size_t)(jbase + j0 + t) * DIN;
        if constexpr (DIN % 4 == 0) {
            #pragma unroll 2
            for (int d = 0; d < DIN; d += 4) {
                float4 v[4];
                #pragma unroll
                for (int u = 0; u < 4; ++u)
                    v[u] = *(const float4*)(xr0 + (size_t)u * 256 * DIN + d);
                #pragma unroll
                for (int q = 0; q < 8; ++q) {
                    float w0 = xq[q][d], w1 = xq[q][d + 1], w2 = xq[q][d + 2], w3 = xq[q][d + 3];
                    #pragma unroll
                    for (int u = 0; u < 4; ++u) {
                        float a = acc[u][q];
                        a = fmaf(v[u].x, w0, a);
                        a = fmaf(v[u].y, w1, a);
                        a = fmaf(v[u].z, w2, a);
                        a = fmaf(v[u].w, w3, a);
                        acc[u][q] = a;
                    }
                }
            }
        } else {
            for (int d = 0; d < DIN; ++d) {
                #pragma unroll
                for (int q = 0; q < 8; ++q) {
                    float w = xq[q][d];
                    #pragma unroll
                    for (int u = 0; u < 4; ++u)
                        acc[u][q] = fmaf(xr0[(size_t)u * 256 * DIN + d], w, acc[u][q]);
                }
            }
        }
        #pragma unroll
        for (int u = 0; u < 4; ++u) {
            int j = j0 + t + u * 256;
            float sj = SQ[jbase + j];
            #pragma unroll
            for (int q = 0; q < 8; ++q)
                dist[q][j] = (sqq[q] + sj) - 2.f * acc[u][q];
        }
    }
    __syncthreads();

    const int w = t >> 6, lane = t & 63;
    #pragma unroll
    for (int qi = 0; qi < 2; ++qi) {
        const int q = w + qi * 4;
        float* dq = &dist[q][0];
        for (int rep = 0; rep < KNN; ++rep) {
            float best = INFINITY;
            int bj = NPTS;
            for (int s = 0; s < NPTS / 64; ++s) {
                int j = lane + (s << 6);
                float v = dq[j];
                if (v < best) { best = v; bj = j; }   // ascending j -> smallest idx on ties
            }
            #pragma unroll
            for (int off = 1; off < 64; off <<= 1) {
                float ov = __shfl_xor(best, off);
                int oj = __shfl_xor(bj, off);
                if (ov < best || (ov == best && oj < bj)) { best = ov; bj = oj; }
            }
            // all lanes now agree on (best, bj)
            if ((bj & 63) == lane) dq[bj] = INFINITY;   // owner poisons its own slot
            if (lane == 0) IDX[(size_t)(qbase + q) * KNN + rep] = bj;
            __asm__ volatile("" ::: "memory");          // keep LDS order; no runtime cost
        }
    }
}

// ---------------- generic tiled GEMM: C[M,N] = A[M,K]@B[K,N] + bias ----------------
template <int KK, int NN>
__global__ __launch_bounds__(256) void gemm_pq_kernel(const float* __restrict__ A,
                                                      const float* __restrict__ B,
                                                      const float* __restrict__ bias,
                                                      float* __restrict__ C) {
    __shared__ float As[16][68];   // K-major: As[r][m]
    __shared__ float Bs[16][64];
    const int t = threadIdx.x;
    const int tx = t & 15, ty = t >> 4;
    const int m0 = blockIdx.x * 64;
    const int c0 = blockIdx.y * 64;
    float acc[4][4];
    #pragma unroll
    for (int i = 0; i < 4; ++i)
        #pragma unroll
        for (int j = 0; j < 4; ++j) acc[i][j] = 0.f;

    constexpr int KCH = (KK + 15) / 16;
    for (int kc = 0; kc < KCH; ++kc) {
        const int k0 = kc * 16;
        {   // A tile
            int m = t & 63;
            int r4 = (t >> 6) * 4;
            if constexpr (KK % 16 == 0) {
                float4 v = *(const float4*)(A + (size_t)(m0 + m) * KK + k0 + r4);
                As[r4 + 0][m] = v.x; As[r4 + 1][m] = v.y;
                As[r4 + 2][m] = v.z; As[r4 + 3][m] = v.w;
            } else {
                #pragma unroll
                for (int i = 0; i < 4; ++i) {
                    int r = r4 + i;
                    As[r][m] = (k0 + r < KK) ? A[(size_t)(m0 + m) * KK + k0 + r] : 0.f;
                }
            }
        }
        {   // B tile
            int r = t >> 4;
            int c = (t & 15) * 4;
            float4 v = make_float4(0.f, 0.f, 0.f, 0.f);
            if (k0 + r < KK) v = *(const float4*)(B + (size_t)(k0 + r) * NN + c0 + c);
            *(float4*)&Bs[r][c] = v;
        }
        __syncthreads();
        #pragma unroll
        for (int r = 0; r < 16; ++r) {
            float4 a4 = *(const float4*)&As[r][ty * 4];
            float4 b4 = *(const float4*)&Bs[r][tx * 4];
            float av[4] = {a4.x, a4.y, a4.z, a4.w};
            float bv[4] = {b4.x, b4.y, b4.z, b4.w};
            #pragma unroll
            for (int i = 0; i < 4; ++i)
                #pragma unroll
                for (int j = 0; j < 4; ++j)
                    acc[i][j] = fmaf(av[i], bv[j], acc[i][j]);
        }
        __syncthreads();
    }
    float4 bv4 = *(const float4*)(bias + c0 + tx * 4);
    float bv[4] = {bv4.x, bv4.y, bv4.z, bv4.w};
    #pragma unroll
    for (int i = 0; i < 4; ++i) {
        float4 o;
        o.x = acc[i][0] + bv[0];
        o.y = acc[i][1] + bv[1];
        o.z = acc[i][2] + bv[2];
        o.w = acc[i][3] + bv[3];
        *(float4*)(C + (size_t)(m0 + ty * 4 + i) * NN + c0 + tx * 4) = o;
    }
}

// ---------------- edge: gather relu(P_i+Q_j) -> @W2+b2 -> relu -> mean_k ----------------
template <int D2, int DOUT>
__global__ __launch_bounds__(256) void edge_kernel(const float* __restrict__ PQ,  // [BN][2*D2]
                                                   const int* __restrict__ IDX,
                                                   const float* __restrict__ W2,  // [D2][DOUT]
                                                   const float* __restrict__ b2,  // [DOUT]
                                                   float* __restrict__ Xn) {      // [BN][DOUT]
    constexpr int N4 = 2 * D2;
    __shared__ float As[16][68];   // K-major: As[r][edge]
    __shared__ float Bs[16][64];   // also reused as reduction buffer
    __shared__ int gjs[64];
    const int t = threadIdx.x;
    const int tx = t & 15, ty = t >> 4;
    const int nb = blockIdx.x * 4;      // node base (4 nodes = 64 edges)
    const int c0 = blockIdx.y * 64;

    if (t < 64) {
        int node = nb + (t >> 4);
        int bstart = (node / NPTS) * NPTS;
        gjs[t] = bstart + IDX[(size_t)node * KNN + (t & 15)];
    }
    __syncthreads();

    float acc[4][4];
    #pragma unroll
    for (int i = 0; i < 4; ++i)
        #pragma unroll
        for (int j = 0; j < 4; ++j) acc[i][j] = 0.f;

    const int e = t & 63;
    const int r4 = (t >> 6) * 4;
    const int gi = nb + (e >> 4);

    for (int k0 = 0; k0 < D2; k0 += 16) {
        {   // A tile: relu(P_i + Q_j)
            int gj = gjs[e];
            float4 p = *(const float4*)(PQ + (size_t)gi * N4 + k0 + r4);
            float4 q = *(const float4*)(PQ + (size_t)gj * N4 + D2 + k0 + r4);
            As[r4 + 0][e] = fmaxf(p.x + q.x, 0.f);
            As[r4 + 1][e] = fmaxf(p.y + q.y, 0.f);
            As[r4 + 2][e] = fmaxf(p.z + q.z, 0.f);
            As[r4 + 3][e] = fmaxf(p.w + q.w, 0.f);
        }
        {   // B tile (W2)
            int r = t >> 4;
            int c = (t & 15) * 4;
            float4 v = make_float4(0.f, 0.f, 0.f, 0.f);
            if (c0 + c < DOUT) v = *(const float4*)(W2 + (size_t)(k0 + r) * DOUT + c0 + c);
            *(float4*)&Bs[r][c] = v;
        }
        __syncthreads();
        #pragma unroll
        for (int r = 0; r < 16; ++r) {
            float4 a4 = *(const float4*)&As[r][ty * 4];
            float4 b4 = *(const float4*)&Bs[r][tx * 4];
            float av[4] = {a4.x, a4.y, a4.z, a4.w};
            float bv[4] = {b4.x, b4.y, b4.z, b4.w};
            #pragma unroll
            for (int i = 0; i < 4; ++i)
                #pragma unroll
                for (int j = 0; j < 4; ++j)
                    acc[i][j] = fmaf(av[i], bv[j], acc[i][j]);
        }
        __syncthreads();
    }

    // epilogue: +b2, relu, sum 4 rows per thread, then 4-way combine -> mean/16
    float bv[4];
    #pragma unroll
    for (int j = 0; j < 4; ++j) {
        int c = c0 + tx * 4 + j;
        bv[j] = (c < DOUT) ? b2[c] : 0.f;
    }
    float s[4];
    #pragma unroll
    for (int j = 0; j < 4; ++j) {
        float ss = 0.f;
        #pragma unroll
        for (int i = 0; i < 4; ++i) ss += fmaxf(acc[i][j] + bv[j], 0.f);
        s[j] = ss;
    }
    #pragma unroll
    for (int j = 0; j < 4; ++j) Bs[ty][tx * 4 + j] = s[j];
    __syncthreads();
    if ((ty & 3) == 0) {
        int node = nb + (ty >> 2);
        #pragma unroll
        for (int j = 0; j < 4; ++j) {
            int c = c0 + tx * 4 + j;
            if (c < DOUT) {
                int cc = tx * 4 + j;
                float tot = Bs[ty][cc] + Bs[ty + 1][cc] + Bs[ty + 2][cc] + Bs[ty + 3][cc];
                Xn[(size_t)node * DOUT + c] = tot * (1.f / 16.f);
            }
        }
    }
}

// ---------------- final: mean over nodes + 16x2 projection ----------------
__global__ __launch_bounds__(256) void final_kernel(const float* __restrict__ X,
                                                    const float* __restrict__ Wf,
                                                    const float* __restrict__ bfin,
                                                    float* __restrict__ out) {
    __shared__ float red[16][17];
    __shared__ float pool[16];
    const int b = blockIdx.x;
    const int t = threadIdx.x;
    const int c = t & 15, rg = t >> 4;
    float s = 0.f;
    for (int n = rg; n < NPTS; n += 16) s += X[(size_t)(b * NPTS + n) * 16 + c];
    red[rg][c] = s;
    __syncthreads();
    if (t < 16) {
        float tot = 0.f;
        #pragma unroll
        for (int i = 0; i < 16; ++i) tot += red[i][t];
        pool[t] = tot * (1.f / NPTS);
    }
    __syncthreads();
    if (t < 2) {
        float a = bfin[t];
        #pragma unroll
        for (int cc = 0; cc < 16; ++cc) a = fmaf(pool[cc], Wf[cc * 2 + t], a);
        out[b * 2 + t] = a;
    }
}

// ---------------- per-layer driver ----------------
template <int DIN, int DOUT>
static void run_layer(const float* Xin, float* Xout, float* PQ, float* SQ, int* IDX,
                      float* WCAT, float* BCAT,
                      const float* W1, const float* b1, const float* W2, const float* b2,
                      hipStream_t stream) {
    constexpr int D2 = 2 * DOUT;
    constexpr int N4 = 2 * D2;
    sq_kernel<<<BN / 256, 256, 0, stream>>>(Xin, SQ, DIN);
    knn_kernel<DIN><<<BN / 8, 256, 0, stream>>>(Xin, SQ, IDX);
    int prep_total = DIN * N4;
    prep_wcat_kernel<<<(prep_total + 255) / 256, 256, 0, stream>>>(W1, b1, WCAT, BCAT, DIN, D2);
    dim3 g1(BN / 64, N4 / 64);
    gemm_pq_kernel<DIN, N4><<<g1, 256, 0, stream>>>(Xin, WCAT, BCAT, PQ);
    dim3 g2(BN / 4, (DOUT + 63) / 64);
    edge_kernel<D2, DOUT><<<g2, 256, 0, stream>>>(PQ, IDX, W2, b2, Xout);
}

extern "C" void kernel_launch(void* const* d_in, const int* in_sizes, int n_in,
                              void* d_out, int out_size, void* d_ws, size_t ws_size,
                              hipStream_t stream) {
    (void)in_sizes; (void)n_in; (void)out_size; (void)ws_size;
    const float* x = (const float*)d_in[0];
    const float* W1a[6]; const float* b1a[6]; const float* W2a[6]; const float* b2a[6];
    for (int l = 0; l < 6; ++l) {
        W1a[l] = (const float*)d_in[1 + 4 * l];
        b1a[l] = (const float*)d_in[2 + 4 * l];
        W2a[l] = (const float*)d_in[3 + 4 * l];
        b2a[l] = (const float*)d_in[4 + 4 * l];
    }
    const float* Wf = (const float*)d_in[25];
    const float* bfin = (const float*)d_in[26];

    float* ws = (float*)d_ws;
    float* X0   = ws;                                   // 16384*256
    float* X1   = X0 + (size_t)BN * 256;                // 16384*256
    float* PQ   = X1 + (size_t)BN * 256;                // 16384*1024
    float* SQ   = PQ + (size_t)BN * 1024;               // 16384
    int*   IDX  = (int*)(SQ + BN);                      // 16384*16
    float* WCAT = (float*)(IDX + (size_t)BN * KNN);     // 131072
    float* BCAT = WCAT + 131072;                        // 1024

    run_layer<3,   32>(x,  X0, PQ, SQ, IDX, WCAT, BCAT, W1a[0], b1a[0], W2a[0], b2a[0], stream);
    run_layer<32, 128>(X0, X1, PQ, SQ, IDX, WCAT, BCAT, W1a[1], b1a[1], W2a[1], b2a[1], stream);
    run_layer<128,256>(X1, X0, PQ, SQ, IDX, WCAT, BCAT, W1a[2], b1a[2], W2a[2], b2a[2], stream);
    run_layer<256, 64>(X0, X1, PQ, SQ, IDX, WCAT, BCAT, W1a[3], b1a[3], W2a[3], b2a[3], stream);
    run_layer<64,  32>(X1, X0, PQ, SQ, IDX, WCAT, BCAT, W1a[4], b1a[4], W2a[4], b2a[4], stream);
    run_layer<32,  16>(X0, X1, PQ, SQ, IDX, WCAT, BCAT, W1a[5], b1a[5], W2a[5], b2a[5], stream);
    final_kernel<<<NB, 256, 0, stream>>>(X1, Wf, bfin, (float*)d_out);
}

// Round 3
// 3155.047 us; speedup vs baseline: 1.4947x; 1.0535x over previous
//
#include <hip/hip_runtime.h>
#include <math.h>

#define NPTS 2048
#define NB 8
#define BN 16384   // NB*NPTS
#define KNN 16

// ---------------- sq: per-node squared norm ----------------
__global__ __launch_bounds__(256) void sq_kernel(const float* __restrict__ X,
                                                 float* __restrict__ SQ, int din) {
    int g = blockIdx.x * 256 + threadIdx.x;
    if (g >= BN) return;
    const float* row = X + (size_t)g * din;
    float s = 0.f;
    for (int d = 0; d < din; ++d) s = fmaf(row[d], row[d], s);
    SQ[g] = s;
}

// ---------------- prep: Wcat = [W1top - W1bot | W1bot], bcat = [b1 | 0] ----------------
__global__ __launch_bounds__(256) void prep_wcat_kernel(const float* __restrict__ W1,
                                                        const float* __restrict__ b1,
                                                        float* __restrict__ Wcat,
                                                        float* __restrict__ bcat,
                                                        int din, int d2) {
    int n4 = 2 * d2;
    int total = din * n4;
    int i = blockIdx.x * 256 + threadIdx.x;
    if (i < total) {
        int d = i / n4, c = i - d * n4;
        float v;
        if (c < d2) v = W1[d * d2 + c] - W1[(din + d) * d2 + c];
        else        v = W1[(din + d) * d2 + (c - d2)];
        Wcat[i] = v;
    }
    if (i < n4) bcat[i] = (i < d2) ? b1[i] : 0.f;
}

// ---------------- knn: fused distance + top-16 (8 queries / block) ----------------
template <int DIN>
__global__ __launch_bounds__(256) void knn_kernel(const float* __restrict__ X,
                                                  const float* __restrict__ SQ,
                                                  int* __restrict__ IDX) {
    __shared__ float dist[8][NPTS];
    __shared__ float xq[8][(DIN < 4) ? 4 : DIN];
    __shared__ float sqq[8];
    const int t = threadIdx.x;
    const int qbase = blockIdx.x * 8;
    const int jbase = (qbase / NPTS) * NPTS;

    for (int i = t; i < 8 * DIN; i += 256) {
        int q = i / DIN, d = i - q * DIN;
        xq[q][d] = X[(size_t)(qbase + q) * DIN + d];
    }
    if (t < 8) sqq[t] = SQ[qbase + t];
    __syncthreads();

    for (int j0 = 0; j0 < NPTS; j0 += 1024) {
        float acc[4][8];   // [u][q]
        #pragma unroll
        for (int u = 0; u < 4; ++u)
            #pragma unroll
            for (int q = 0; q < 8; ++q) acc[u][q] = 0.f;
        const float* xr0 = X + (size_t)(jbase + j0 + t) * DIN;
        if constexpr (DIN % 4 == 0) {
            #pragma unroll 2
            for (int d = 0; d < DIN; d += 4) {
                float4 v[4];
                #pragma unroll
                for (int u = 0; u < 4; ++u)
                    v[u] = *(const float4*)(xr0 + (size_t)u * 256 * DIN + d);
                #pragma unroll
                for (int q = 0; q < 8; ++q) {
                    float w0 = xq[q][d], w1 = xq[q][d + 1], w2 = xq[q][d + 2], w3 = xq[q][d + 3];
                    #pragma unroll
                    for (int u = 0; u < 4; ++u) {
                        float a = acc[u][q];
                        a = fmaf(v[u].x, w0, a);
                        a = fmaf(v[u].y, w1, a);
                        a = fmaf(v[u].z, w2, a);
                        a = fmaf(v[u].w, w3, a);
                        acc[u][q] = a;
                    }
                }
            }
        } else {
            for (int d = 0; d < DIN; ++d) {
                #pragma unroll
                for (int q = 0; q < 8; ++q) {
                    float w = xq[q][d];
                    #pragma unroll
                    for (int u = 0; u < 4; ++u)
                        acc[u][q] = fmaf(xr0[(size_t)u * 256 * DIN + d], w, acc[u][q]);
                }
            }
        }
        #pragma unroll
        for (int u = 0; u < 4; ++u) {
            int j = j0 + t + u * 256;
            float sj = SQ[jbase + j];
            #pragma unroll
            for (int q = 0; q < 8; ++q)
                dist[q][j] = (sqq[q] + sj) - 2.f * acc[u][q];
        }
    }
    __syncthreads();

    const int w = t >> 6, lane = t & 63;
    #pragma unroll
    for (int qi = 0; qi < 2; ++qi) {
        const int q = w + qi * 4;
        float* dq = &dist[q][0];
        for (int rep = 0; rep < KNN; ++rep) {
            float best = INFINITY;
            int bj = NPTS;
            for (int s = 0; s < NPTS / 64; ++s) {
                int j = lane + (s << 6);
                float v = dq[j];
                if (v < best) { best = v; bj = j; }
            }
            #pragma unroll
            for (int off = 1; off < 64; off <<= 1) {
                float ov = __shfl_xor(best, off);
                int oj = __shfl_xor(bj, off);
                if (ov < best || (ov == best && oj < bj)) { best = ov; bj = oj; }
            }
            if ((bj & 63) == lane) dq[bj] = INFINITY;
            if (lane == 0) IDX[(size_t)(qbase + q) * KNN + rep] = bj;
            __asm__ volatile("" ::: "memory");
        }
    }
}

// ---------------- generic tiled GEMM: C[M,N] = A[M,K]@B[K,N] + bias ----------------
template <int KK, int NN>
__global__ __launch_bounds__(256) void gemm_pq_kernel(const float* __restrict__ A,
                                                      const float* __restrict__ B,
                                                      const float* __restrict__ bias,
                                                      float* __restrict__ C) {
    __shared__ float As[16][68];
    __shared__ float Bs[16][64];
    const int t = threadIdx.x;
    const int tx = t & 15, ty = t >> 4;
    const int m0 = blockIdx.x * 64;
    const int c0 = blockIdx.y * 64;
    float acc[4][4];
    #pragma unroll
    for (int i = 0; i < 4; ++i)
        #pragma unroll
        for (int j = 0; j < 4; ++j) acc[i][j] = 0.f;

    constexpr int KCH = (KK + 15) / 16;
    for (int kc = 0; kc < KCH; ++kc) {
        const int k0 = kc * 16;
        {
            int m = t & 63;
            int r4 = (t >> 6) * 4;
            if constexpr (KK % 16 == 0) {
                float4 v = *(const float4*)(A + (size_t)(m0 + m) * KK + k0 + r4);
                As[r4 + 0][m] = v.x; As[r4 + 1][m] = v.y;
                As[r4 + 2][m] = v.z; As[r4 + 3][m] = v.w;
            } else {
                #pragma unroll
                for (int i = 0; i < 4; ++i) {
                    int r = r4 + i;
                    As[r][m] = (k0 + r < KK) ? A[(size_t)(m0 + m) * KK + k0 + r] : 0.f;
                }
            }
        }
        {
            int r = t >> 4;
            int c = (t & 15) * 4;
            float4 v = make_float4(0.f, 0.f, 0.f, 0.f);
            if (k0 + r < KK) v = *(const float4*)(B + (size_t)(k0 + r) * NN + c0 + c);
            *(float4*)&Bs[r][c] = v;
        }
        __syncthreads();
        #pragma unroll
        for (int r = 0; r < 16; ++r) {
            float4 a4 = *(const float4*)&As[r][ty * 4];
            float4 b4 = *(const float4*)&Bs[r][tx * 4];
            float av[4] = {a4.x, a4.y, a4.z, a4.w};
            float bv[4] = {b4.x, b4.y, b4.z, b4.w};
            #pragma unroll
            for (int i = 0; i < 4; ++i)
                #pragma unroll
                for (int j = 0; j < 4; ++j)
                    acc[i][j] = fmaf(av[i], bv[j], acc[i][j]);
        }
        __syncthreads();
    }
    float4 bv4 = *(const float4*)(bias + c0 + tx * 4);
    float bv[4] = {bv4.x, bv4.y, bv4.z, bv4.w};
    #pragma unroll
    for (int i = 0; i < 4; ++i) {
        float4 o;
        o.x = acc[i][0] + bv[0];
        o.y = acc[i][1] + bv[1];
        o.z = acc[i][2] + bv[2];
        o.w = acc[i][3] + bv[3];
        *(float4*)(C + (size_t)(m0 + ty * 4 + i) * NN + c0 + tx * 4) = o;
    }
}

// ---------------- edge small (DOUT<=64): 64 edges x 64 cols, 4x4/thread ----------------
template <int D2, int DOUT>
__global__ __launch_bounds__(256) void edge_kernel(const float* __restrict__ PQ,
                                                   const int* __restrict__ IDX,
                                                   const float* __restrict__ W2,
                                                   const float* __restrict__ b2,
                                                   float* __restrict__ Xn) {
    constexpr int N4 = 2 * D2;
    __shared__ float As[16][68];
    __shared__ float Bs[16][64];
    __shared__ int gjs[64];
    const int t = threadIdx.x;
    const int tx = t & 15, ty = t >> 4;
    const int nb = blockIdx.x * 4;
    const int c0 = blockIdx.y * 64;

    if (t < 64) {
        int node = nb + (t >> 4);
        int bstart = (node / NPTS) * NPTS;
        gjs[t] = bstart + IDX[(size_t)node * KNN + (t & 15)];
    }
    __syncthreads();

    float acc[4][4];
    #pragma unroll
    for (int i = 0; i < 4; ++i)
        #pragma unroll
        for (int j = 0; j < 4; ++j) acc[i][j] = 0.f;

    const int e = t & 63;
    const int r4 = (t >> 6) * 4;
    const int gi = nb + (e >> 4);

    for (int k0 = 0; k0 < D2; k0 += 16) {
        {
            int gj = gjs[e];
            float4 p = *(const float4*)(PQ + (size_t)gi * N4 + k0 + r4);
            float4 q = *(const float4*)(PQ + (size_t)gj * N4 + D2 + k0 + r4);
            As[r4 + 0][e] = fmaxf(p.x + q.x, 0.f);
            As[r4 + 1][e] = fmaxf(p.y + q.y, 0.f);
            As[r4 + 2][e] = fmaxf(p.z + q.z, 0.f);
            As[r4 + 3][e] = fmaxf(p.w + q.w, 0.f);
        }
        {
            int r = t >> 4;
            int c = (t & 15) * 4;
            float4 v = make_float4(0.f, 0.f, 0.f, 0.f);
            if (c0 + c < DOUT) v = *(const float4*)(W2 + (size_t)(k0 + r) * DOUT + c0 + c);
            *(float4*)&Bs[r][c] = v;
        }
        __syncthreads();
        #pragma unroll
        for (int r = 0; r < 16; ++r) {
            float4 a4 = *(const float4*)&As[r][ty * 4];
            float4 b4 = *(const float4*)&Bs[r][tx * 4];
            float av[4] = {a4.x, a4.y, a4.z, a4.w};
            float bv[4] = {b4.x, b4.y, b4.z, b4.w};
            #pragma unroll
            for (int i = 0; i < 4; ++i)
                #pragma unroll
                for (int j = 0; j < 4; ++j)
                    acc[i][j] = fmaf(av[i], bv[j], acc[i][j]);
        }
        __syncthreads();
    }

    float bv[4];
    #pragma unroll
    for (int j = 0; j < 4; ++j) {
        int c = c0 + tx * 4 + j;
        bv[j] = (c < DOUT) ? b2[c] : 0.f;
    }
    float s[4];
    #pragma unroll
    for (int j = 0; j < 4; ++j) {
        float ss = 0.f;
        #pragma unroll
        for (int i = 0; i < 4; ++i) ss += fmaxf(acc[i][j] + bv[j], 0.f);
        s[j] = ss;
    }
    #pragma unroll
    for (int j = 0; j < 4; ++j) Bs[ty][tx * 4 + j] = s[j];
    __syncthreads();
    if ((ty & 3) == 0) {
        int node = nb + (ty >> 2);
        #pragma unroll
        for (int j = 0; j < 4; ++j) {
            int c = c0 + tx * 4 + j;
            if (c < DOUT) {
                int cc = tx * 4 + j;
                float tot = Bs[ty][cc] + Bs[ty + 1][cc] + Bs[ty + 2][cc] + Bs[ty + 3][cc];
                Xn[(size_t)node * DOUT + c] = tot * (1.f / 16.f);
            }
        }
    }
}

// ---------------- edge big (DOUT>=128): 128 edges x 128 cols, 8x8/thread ----------------
// LDS rows padded to 132 floats: all ds accesses land at <=2-way bank aliasing (free).
// Rows/cols split 4+4 (ty*4 / 64+ty*4, tx*4 / 64+tx*4) to keep float4 LDS ops.
template <int D2, int DOUT>
__global__ __launch_bounds__(256) void edge_big_kernel(const float* __restrict__ PQ,
                                                       const int* __restrict__ IDX,
                                                       const float* __restrict__ W2,
                                                       const float* __restrict__ b2,
                                                       float* __restrict__ Xn) {
    constexpr int N4 = 2 * D2;
    __shared__ float As[16][132];
    __shared__ float Bs[16][132];
    __shared__ int gjs[128];
    const int t = threadIdx.x;
    const int tx = t & 15, ty = t >> 4;
    const int nb8 = blockIdx.x * 8;       // 8 nodes = 128 edges
    const int c0 = blockIdx.y * 128;

    if (t < 128) {
        int node = nb8 + (t >> 4);
        int bstart = (node / NPTS) * NPTS;
        gjs[t] = bstart + IDX[(size_t)node * KNN + (t & 15)];
    }
    __syncthreads();

    float acc[8][8];
    #pragma unroll
    for (int i = 0; i < 8; ++i)
        #pragma unroll
        for (int j = 0; j < 8; ++j) acc[i][j] = 0.f;

    // A-staging assignment: thread covers edge e, k-rows rh..rh+7
    const int e = t & 127;
    const int rh = (t >> 7) * 8;
    const int gi = nb8 + (e >> 4);
    const int gj = gjs[e];
    const float* Prow = PQ + (size_t)gi * N4;
    const float* Qrow = PQ + (size_t)gj * N4 + D2;
    // B-staging assignment
    const int br = t & 15;
    const int bc = (t >> 4) * 8;
    const float* Wbase = W2 + (size_t)br * DOUT + c0 + bc;

    for (int k0 = 0; k0 < D2; k0 += 16) {
        {   // A tile: relu(P_i + Q_j), K-major
            float4 p0 = *(const float4*)(Prow + k0 + rh);
            float4 p1 = *(const float4*)(Prow + k0 + rh + 4);
            float4 q0 = *(const float4*)(Qrow + k0 + rh);
            float4 q1 = *(const float4*)(Qrow + k0 + rh + 4);
            As[rh + 0][e] = fmaxf(p0.x + q0.x, 0.f);
            As[rh + 1][e] = fmaxf(p0.y + q0.y, 0.f);
            As[rh + 2][e] = fmaxf(p0.z + q0.z, 0.f);
            As[rh + 3][e] = fmaxf(p0.w + q0.w, 0.f);
            As[rh + 4][e] = fmaxf(p1.x + q1.x, 0.f);
            As[rh + 5][e] = fmaxf(p1.y + q1.y, 0.f);
            As[rh + 6][e] = fmaxf(p1.z + q1.z, 0.f);
            As[rh + 7][e] = fmaxf(p1.w + q1.w, 0.f);
        }
        {   // B tile
            const float* w = Wbase + (size_t)k0 * DOUT;
            float4 w0 = *(const float4*)(w);
            float4 w1 = *(const float4*)(w + 4);
            *(float4*)&Bs[br][bc] = w0;
            *(float4*)&Bs[br][bc + 4] = w1;
        }
        __syncthreads();
        #pragma unroll
        for (int r = 0; r < 16; ++r) {
            float4 a0 = *(const float4*)&As[r][ty * 4];
            float4 a1 = *(const float4*)&As[r][64 + ty * 4];
            float4 b0 = *(const float4*)&Bs[r][tx * 4];
            float4 b1 = *(const float4*)&Bs[r][64 + tx * 4];
            float av[8] = {a0.x, a0.y, a0.z, a0.w, a1.x, a1.y, a1.z, a1.w};
            float bv[8] = {b0.x, b0.y, b0.z, b0.w, b1.x, b1.y, b1.z, b1.w};
            #pragma unroll
            for (int i = 0; i < 8; ++i)
                #pragma unroll
                for (int j = 0; j < 8; ++j)
                    acc[i][j] = fmaf(av[i], bv[j], acc[i][j]);
        }
        __syncthreads();
    }

    // epilogue: +b2, relu per edge-row, partial sums into LDS, then mean/16
    // rows ty*4..+3 (half0, nodes 0..3) -> As[ty][col]; rows 64+ty*4..+3 (half1, nodes 4..7) -> Bs[ty][col]
    #pragma unroll
    for (int j = 0; j < 8; ++j) {
        int cl = (j < 4) ? (tx * 4 + j) : (64 + tx * 4 + (j - 4));
        float bb = b2[c0 + cl];
        float s0 = 0.f, s1 = 0.f;
        #pragma unroll
        for (int i = 0; i < 4; ++i) {
            s0 += fmaxf(acc[i][j] + bb, 0.f);
            s1 += fmaxf(acc[4 + i][j] + bb, 0.f);
        }
        As[ty][cl] = s0;
        Bs[ty][cl] = s1;
    }
    __syncthreads();
    {
        // 8 nodes x 128 cols = 1024 outputs; thread t handles 4 consecutive cols
        int node = t >> 5;                  // 0..7
        int colb = (t * 4) & 127;
        int tg = (node & 3) * 4;            // row group base within half
        float4 o;
        float v0, v1, v2, v3;
        if (node < 4) {
            v0 = As[tg + 0][colb + 0] + As[tg + 1][colb + 0] + As[tg + 2][colb + 0] + As[tg + 3][colb + 0];
            v1 = As[tg + 0][colb + 1] + As[tg + 1][colb + 1] + As[tg + 2][colb + 1] + As[tg + 3][colb + 1];
            v2 = As[tg + 0][colb + 2] + As[tg + 1][colb + 2] + As[tg + 2][colb + 2] + As[tg + 3][colb + 2];
            v3 = As[tg + 0][colb + 3] + As[tg + 1][colb + 3] + As[tg + 2][colb + 3] + As[tg + 3][colb + 3];
        } else {
            v0 = Bs[tg + 0][colb + 0] + Bs[tg + 1][colb + 0] + Bs[tg + 2][colb + 0] + Bs[tg + 3][colb + 0];
            v1 = Bs[tg + 0][colb + 1] + Bs[tg + 1][colb + 1] + Bs[tg + 2][colb + 1] + Bs[tg + 3][colb + 1];
            v2 = Bs[tg + 0][colb + 2] + Bs[tg + 1][colb + 2] + Bs[tg + 2][colb + 2] + Bs[tg + 3][colb + 2];
            v3 = Bs[tg + 0][colb + 3] + Bs[tg + 1][colb + 3] + Bs[tg + 2][colb + 3] + Bs[tg + 3][colb + 3];
        }
        o.x = v0 * (1.f / 16.f); o.y = v1 * (1.f / 16.f);
        o.z = v2 * (1.f / 16.f); o.w = v3 * (1.f / 16.f);
        *(float4*)(Xn + (size_t)(nb8 + node) * DOUT + c0 + colb) = o;
    }
}

// ---------------- final: mean over nodes + 16x2 projection ----------------
__global__ __launch_bounds__(256) void final_kernel(const float* __restrict__ X,
                                                    const float* __restrict__ Wf,
                                                    const float* __restrict__ bfin,
                                                    float* __restrict__ out) {
    __shared__ float red[16][17];
    __shared__ float pool[16];
    const int b = blockIdx.x;
    const int t = threadIdx.x;
    const int c = t & 15, rg = t >> 4;
    float s = 0.f;
    for (int n = rg; n < NPTS; n += 16) s += X[(size_t)(b * NPTS + n) * 16 + c];
    red[rg][c] = s;
    __syncthreads();
    if (t < 16) {
        float tot = 0.f;
        #pragma unroll
        for (int i = 0; i < 16; ++i) tot += red[i][t];
        pool[t] = tot * (1.f / NPTS);
    }
    __syncthreads();
    if (t < 2) {
        float a = bfin[t];
        #pragma unroll
        for (int cc = 0; cc < 16; ++cc) a = fmaf(pool[cc], Wf[cc * 2 + t], a);
        out[b * 2 + t] = a;
    }
}

// ---------------- per-layer driver ----------------
template <int DIN, int DOUT>
static void run_layer(const float* Xin, float* Xout, float* PQ, float* SQ, int* IDX,
                      float* WCAT, float* BCAT,
                      const float* W1, const float* b1, const float* W2, const float* b2,
                      hipStream_t stream) {
    constexpr int D2 = 2 * DOUT;
    constexpr int N4 = 2 * D2;
    sq_kernel<<<BN / 256, 256, 0, stream>>>(Xin, SQ, DIN);
    knn_kernel<DIN><<<BN / 8, 256, 0, stream>>>(Xin, SQ, IDX);
    int prep_total = DIN * N4;
    prep_wcat_kernel<<<(prep_total + 255) / 256, 256, 0, stream>>>(W1, b1, WCAT, BCAT, DIN, D2);
    dim3 g1(BN / 64, N4 / 64);
    gemm_pq_kernel<DIN, N4><<<g1, 256, 0, stream>>>(Xin, WCAT, BCAT, PQ);
    if constexpr (DOUT >= 128) {
        dim3 g2(BN / 8, DOUT / 128);
        edge_big_kernel<D2, DOUT><<<g2, 256, 0, stream>>>(PQ, IDX, W2, b2, Xout);
    } else {
        dim3 g2(BN / 4, (DOUT + 63) / 64);
        edge_kernel<D2, DOUT><<<g2, 256, 0, stream>>>(PQ, IDX, W2, b2, Xout);
    }
}

extern "C" void kernel_launch(void* const* d_in, const int* in_sizes, int n_in,
                              void* d_out, int out_size, void* d_ws, size_t ws_size,
                              hipStream_t stream) {
    (void)in_sizes; (void)n_in; (void)out_size; (void)ws_size;
    const float* x = (const float*)d_in[0];
    const float* W1a[6]; const float* b1a[6]; const float* W2a[6]; const float* b2a[6];
    for (int l = 0; l < 6; ++l) {
        W1a[l] = (const float*)d_in[1 + 4 * l];
        b1a[l] = (const float*)d_in[2 + 4 * l];
        W2a[l] = (const float*)d_in[3 + 4 * l];
        b2a[l] = (const float*)d_in[4 + 4 * l];
    }
    const float* Wf = (const float*)d_in[25];
    const float* bfin = (const float*)d_in[26];

    float* ws = (float*)d_ws;
    float* X0   = ws;                                   // 16384*256
    float* X1   = X0 + (size_t)BN * 256;                // 16384*256
    float* PQ   = X1 + (size_t)BN * 256;                // 16384*1024
    float* SQ   = PQ + (size_t)BN * 1024;               // 16384
    int*   IDX  = (int*)(SQ + BN);                      // 16384*16
    float* WCAT = (float*)(IDX + (size_t)BN * KNN);     // 131072
    float* BCAT = WCAT + 131072;                        // 1024

    run_layer<3,   32>(x,  X0, PQ, SQ, IDX, WCAT, BCAT, W1a[0], b1a[0], W2a[0], b2a[0], stream);
    run_layer<32, 128>(X0, X1, PQ, SQ, IDX, WCAT, BCAT, W1a[1], b1a[1], W2a[1], b2a[1], stream);
    run_layer<128,256>(X1, X0, PQ, SQ, IDX, WCAT, BCAT, W1a[2], b1a[2], W2a[2], b2a[2], stream);
    run_layer<256, 64>(X0, X1, PQ, SQ, IDX, WCAT, BCAT, W1a[3], b1a[3], W2a[3], b2a[3], stream);
    run_layer<64,  32>(X1, X0, PQ, SQ, IDX, WCAT, BCAT, W1a[4], b1a[4], W2a[4], b2a[4], stream);
    run_layer<32,  16>(X0, X1, PQ, SQ, IDX, WCAT, BCAT, W1a[5], b1a[5], W2a[5], b2a[5], stream);
    final_kernel<<<NB, 256, 0, stream>>>(X1, Wf, bfin, (float*)d_out);
}